// Round 14
// baseline (289.141 us; speedup 1.0000x reference)
//
#include <hip/hip_runtime.h>
#include <hip/hip_bf16.h>
#include <hip/hip_fp16.h>
#include <stdint.h>

// LightGCN on MI355X, round 17.
// R16 confirmed 284.3us (TLP edits: k_build 196x1024 no-redundancy,
// k_bucket 512t). spmv x3 @58.6 = 176us probed floor. Last non-floor
// item: k_bucket (~40-45us, LDS-atomic bound; BW floor ~8us).
// R17: direct-placement k_bucket. Deletes phase A (count) + phase B scan:
// per-bucket fixed LDS regions (196 x 56 slots, stride 57 = odd => banks
// decorrelated across buckets), 1 LDS atomic places each edge; one global
// reservation atomic per bucket after counting; flush contiguous runs.
// Per edge: 1 atomic + 1 store (was 2+2), col read once (was twice).
// CHUNK 4096 -> runs avg 21 >= 16-entry line rule (R12 lesson); LDS
// 46.3KB < 64KB static cap; 1024 threads -> 2 blocks/CU = 32 waves/CU.
// Overflow: 56 slots = 7.8 sigma over Poisson(21), clamped (P~5e-10).
// k_build/k_z0/spmv = R16 verbatim.

#define N_NODES 100000
#define N_EDGES 3200000
#define DIM 64

#define BSH 9                // 512 nodes per bucket
#define BNODES 512
#define NB 196               // ceil(100000/512)
#define CAP 20480            // staging slots per bucket (mean 16327)

#define CHUNK 4096           // edges per k_bucket block
#define NBLK1 ((N_EDGES + CHUNK - 1) / CHUNK)  // 782
#define CAPR 56              // LDS slots per bucket region
#define RSTRIDE 57           // padded stride (bank decorrelation)

// ---- level 1: bucket edges by dst range (dst>>9); direct placement ----
__global__ __launch_bounds__(1024) void k_bucket(const int* __restrict__ ei,
                                                 int* __restrict__ gcursor,
                                                 int* __restrict__ staging) {
    __shared__ int region[NB * RSTRIDE];   // 196*57*4 = 44.7 KB
    __shared__ int boff[NB];
    __shared__ int gbase[NB];

    int t = threadIdx.x;
    int e0 = blockIdx.x * CHUNK;
    int nblk = min(CHUNK, N_EDGES - e0);
    int nvec = nblk >> 2;

    const int4* col4 = (const int4*)(ei + N_EDGES + e0);
    const int4* row4 = (const int4*)(ei + e0);

    for (int i = t; i < NB; i += 1024) boff[i] = 0;
    __syncthreads();

    // phase C: place edges directly into per-bucket LDS regions
    for (int i = t; i < nvec; i += 1024) {
        int4 c = col4[i];
        int4 r = row4[i];
        int b0 = c.x >> BSH, b1 = c.y >> BSH, b2 = c.z >> BSH, b3 = c.w >> BSH;
        int p0 = atomicAdd(&boff[b0], 1);
        int p1 = atomicAdd(&boff[b1], 1);
        int p2 = atomicAdd(&boff[b2], 1);
        int p3 = atomicAdd(&boff[b3], 1);
        if (p0 < CAPR) region[b0 * RSTRIDE + p0] = (r.x << BSH) | (c.x & (BNODES - 1));
        if (p1 < CAPR) region[b1 * RSTRIDE + p1] = (r.y << BSH) | (c.y & (BNODES - 1));
        if (p2 < CAPR) region[b2 * RSTRIDE + p2] = (r.z << BSH) | (c.z & (BNODES - 1));
        if (p3 < CAPR) region[b3 * RSTRIDE + p3] = (r.w << BSH) | (c.w & (BNODES - 1));
    }
    __syncthreads();

    // phase B': clamp counts; reserve global runs (one atomic per bucket)
    if (t < NB) {
        int v = min(boff[t], CAPR);
        boff[t] = v;
        gbase[t] = (v > 0) ? atomicAdd(&gcursor[t], v) : 0;
    }
    __syncthreads();

    // phase D: flush runs contiguously (valid slots are the low part of
    // each region; writes within a run are consecutive)
    for (int i = t; i < NB * CAPR; i += 1024) {
        int b = i / CAPR;
        int j = i - b * CAPR;
        if (j < boff[b]) {
            staging[(size_t)b * CAP + gbase[b] + j] = region[b * RSTRIDE + j];
        }
    }
}

// ---- level 2: CSR build; ONE block of 1024 threads per bucket ----
// Reads the bucket segment once; counts 512 nodes (3.2M total atomics);
// scans; scatters into the bucket's contiguous csrc range (single owner).
__global__ __launch_bounds__(1024) void k_build(const int* __restrict__ gcursor,
                                                const int* __restrict__ staging,
                                                int4* __restrict__ rec,
                                                float* __restrict__ dinv,
                                                int* __restrict__ csrc) {
    __shared__ int ldeg[BNODES];
    __shared__ int lcur[BNODES];
    __shared__ int gsc[NB];
    __shared__ int wtt[16];

    int b = blockIdx.x;
    int t = threadIdx.x;
    int lane = t & 63, w = t >> 6;
    int n0 = b << BSH;
    int nloc = min(BNODES, N_NODES - n0);
    int cnt = gcursor[b];
    const int* st = staging + (size_t)b * CAP;

    if (t < BNODES) ldeg[t] = 0;

    // bucketStart[b] via in-block exclusive scan of gcursor[0..NB)
    {
        int v = (t < NB) ? gcursor[t] : 0;
        int ss = v;
#pragma unroll
        for (int off = 1; off < 64; off <<= 1) {
            int u = __shfl_up(ss, off);
            if (lane >= off) ss += u;
        }
        if (lane == 63) wtt[w] = ss;
        __syncthreads();
        int wo = 0;
        for (int ww = 0; ww < w; ww++) wo += wtt[ww];
        if (t < NB) gsc[t] = ss - v + wo;
    }
    __syncthreads();
    int bstartB = gsc[b];

    // count the bucket's 512 nodes (single pass, no redundancy)
    for (int i = t; i < cnt; i += 1024) {
        atomicAdd(&ldeg[st[i] & (BNODES - 1)], 1);
    }
    __syncthreads();

    // scan over 512 counters (1 per thread, threads 0..511 over 8 waves)
    int a = (t < BNODES) ? ldeg[t] : 0;
    int ss = a;
#pragma unroll
    for (int off = 1; off < 64; off <<= 1) {
        int u = __shfl_up(ss, off);
        if (lane >= off) ss += u;
    }
    if (lane == 63) wtt[w] = ss;
    __syncthreads();
    int wo = 0;
    for (int ww = 0; ww < w; ww++) wo += wtt[ww];
    int excl = ss - a + wo;

    if (t < BNODES) {
        int gb = bstartB + excl;
        lcur[t] = gb;
        if (t < nloc) {
            int n = n0 + t;
            float di = (a > 0) ? rsqrtf((float)a) : 0.0f;
            rec[n] = make_int4(gb, a, __float_as_int(di), 0);
            dinv[n] = di;
        }
    }
    __syncthreads();

    // scatter into this bucket's csrc range (single owner -> L2 combining)
    for (int i = t; i < cnt; i += 1024) {
        int e = st[i];
        int p = atomicAdd(&lcur[e & (BNODES - 1)], 1);
        csrc[p] = e >> BSH;
    }
}

// z0 = fp16(emb * dinv[node]); tail threads zero the zero rows of zA/zB
__global__ void k_z0(const float* __restrict__ emb, const float* __restrict__ dinv,
                     __half* __restrict__ zA, __half* __restrict__ zB) {
    const int total = (N_NODES * DIM) / 4;  // 1.6M groups of 4
    int i = blockIdx.x * blockDim.x + threadIdx.x;
    if (i >= total) {
        int r = i - total;
        if (r < 16) ((uint2*)(zA + (size_t)N_NODES * DIM))[r] = make_uint2(0, 0);
        else if (r < 32) ((uint2*)(zB + (size_t)N_NODES * DIM))[r - 16] = make_uint2(0, 0);
        return;
    }
    float di = dinv[(i * 4) >> 6];
    const float4 v = ((const float4*)emb)[i];
    union { ushort h[4]; uint2 u; } pk;
    __half h0 = __float2half(v.x * di);
    __half h1 = __float2half(v.y * di);
    __half h2 = __float2half(v.z * di);
    __half h3 = __float2half(v.w * di);
    pk.h[0] = *(ushort*)&h0; pk.h[1] = *(ushort*)&h1;
    pk.h[2] = *(ushort*)&h2; pk.h[3] = *(ushort*)&h3;
    ((uint2*)zA)[i] = pk.u;
}

// ---- SpMV: one wave per dst node; exact ceil(deg/8) gather groups of 8;
// fp16 rows, packed half2 accumulate; invalid slots -> zero row.
// mode 0: write z_out = x*dinv (fp16) only.
// mode 2: final: out = 0.25*(emb + sqrt(deg)*(z2+z3) + x3); no z write.
__global__ __launch_bounds__(256) void k_spmv(
    const int4* __restrict__ rec, const int* __restrict__ csrc,
    const __half* __restrict__ z, __half* __restrict__ znext,
    const __half* __restrict__ zprev, const float* __restrict__ emb,
    float* __restrict__ out, int mode) {
    int wave = (blockIdx.x * blockDim.x + threadIdx.x) >> 6;
    int lane = threadIdx.x & 63;
    if (wave >= N_NODES) return;
    int g = lane >> 3;   // edge slot within group 0..7
    int l = lane & 7;    // feature chunk: features [l*8, l*8+8)

    int4 nr = rec[wave];          // broadcast load
    int start = nr.x;
    int cnt = nr.y;
    float di = __int_as_float(nr.z);
    int ng = (cnt + 7) >> 3;      // gather groups (wave-uniform)

    __half2 hz = __float2half2_rn(0.0f);
    __half2 hacc0 = hz, hacc1 = hz, hacc2 = hz, hacc3 = hz;

#define GIDX(KK, SV)                                 \
    int e_##SV = (KK) * 8 + g;                       \
    int SV = csrc[start + e_##SV];                   \
    SV = (e_##SV < cnt) ? SV : N_NODES;

#define GFETCH(SV, VV)                               \
    uint4 VV = *((const uint4*)(z + ((size_t)SV << 6)) + l);

#define GADD(VV)                                                          \
    do {                                                                  \
        const __half2* hv = (const __half2*)&VV;                          \
        hacc0 = __hadd2(hacc0, hv[0]);                                    \
        hacc1 = __hadd2(hacc1, hv[1]);                                    \
        hacc2 = __hadd2(hacc2, hv[2]);                                    \
        hacc3 = __hadd2(hacc3, hv[3]);                                    \
    } while (0)

    int k = 0;
    for (; k + 4 <= ng; k += 4) {
        GIDX(k + 0, s0) GIDX(k + 1, s1) GIDX(k + 2, s2) GIDX(k + 3, s3)
        GFETCH(s0, v0) GFETCH(s1, v1) GFETCH(s2, v2) GFETCH(s3, v3)
        GADD(v0); GADD(v1); GADD(v2); GADD(v3);
    }
    int rem = ng - k;           // wave-uniform 0..3
    if (rem > 0) {
        GIDX(k + 0, t0)
        if (rem > 1) {
            GIDX(k + 1, t1)
            if (rem > 2) {
                GIDX(k + 2, t2)
                GFETCH(t0, w0) GFETCH(t1, w1) GFETCH(t2, w2)
                GADD(w0); GADD(w1); GADD(w2);
            } else {
                GFETCH(t0, w0) GFETCH(t1, w1)
                GADD(w0); GADD(w1);
            }
        } else {
            GFETCH(t0, w0)
            GADD(w0);
        }
    }
#undef GIDX
#undef GFETCH
#undef GADD

    // packed reduce across the 8 edge-slot groups (lane bits 3,4,5)
#pragma unroll
    for (int off = 8; off <= 32; off <<= 1) {
        int b0 = __shfl_xor(*(int*)&hacc0, off);
        int b1 = __shfl_xor(*(int*)&hacc1, off);
        int b2 = __shfl_xor(*(int*)&hacc2, off);
        int b3 = __shfl_xor(*(int*)&hacc3, off);
        hacc0 = __hadd2(hacc0, *(__half2*)&b0);
        hacc1 = __hadd2(hacc1, *(__half2*)&b1);
        hacc2 = __hadd2(hacc2, *(__half2*)&b2);
        hacc3 = __hadd2(hacc3, *(__half2*)&b3);
    }

    if (lane < 8) {  // lane == l, holds features [l*8, l*8+8)
        size_t o = (size_t)wave * DIM + lane * 8;
        float x[8];   // x_{k+1} for this node = di * sum
        x[0] = __low2float(hacc0) * di; x[1] = __high2float(hacc0) * di;
        x[2] = __low2float(hacc1) * di; x[3] = __high2float(hacc1) * di;
        x[4] = __low2float(hacc2) * di; x[5] = __high2float(hacc2) * di;
        x[6] = __low2float(hacc3) * di; x[7] = __high2float(hacc3) * di;

        if (mode == 0) {
            union { ushort h[8]; uint4 u; } pk;
#pragma unroll
            for (int j = 0; j < 8; j++) {
                __half hh = __float2half(x[j] * di);
                pk.h[j] = *(ushort*)&hh;
            }
            *((uint4*)(znext + o)) = pk.u;
        } else {
            float sdeg = (cnt > 0) ? sqrtf((float)cnt) : 0.0f;
            uint4 v2 = *((const uint4*)(zprev + o));  // z2 (own row)
            uint4 v3 = *((const uint4*)(z + o));      // z3 (own row)
            const __half2* h2 = (const __half2*)&v2;
            const __half2* h3 = (const __half2*)&v3;
            float4 e0 = ((const float4*)(emb + o))[0];
            float4 e1 = ((const float4*)(emb + o))[1];
            float zs[8];
#pragma unroll
            for (int j = 0; j < 4; j++) {
                float2 a2 = __half22float2(h2[j]);
                float2 a3 = __half22float2(h3[j]);
                zs[2 * j] = a2.x + a3.x;
                zs[2 * j + 1] = a2.y + a3.y;
            }
            float4 o0 = make_float4(
                (e0.x + sdeg * zs[0] + x[0]) * 0.25f,
                (e0.y + sdeg * zs[1] + x[1]) * 0.25f,
                (e0.z + sdeg * zs[2] + x[2]) * 0.25f,
                (e0.w + sdeg * zs[3] + x[3]) * 0.25f);
            float4 o1 = make_float4(
                (e1.x + sdeg * zs[4] + x[4]) * 0.25f,
                (e1.y + sdeg * zs[5] + x[5]) * 0.25f,
                (e1.z + sdeg * zs[6] + x[6]) * 0.25f,
                (e1.w + sdeg * zs[7] + x[7]) * 0.25f);
            ((float4*)(out + o))[0] = o0;
            ((float4*)(out + o))[1] = o1;
        }
    }
}

extern "C" void kernel_launch(void* const* d_in, const int* in_sizes, int n_in,
                              void* d_out, int out_size, void* d_ws, size_t ws_size,
                              hipStream_t stream) {
    const float* emb = (const float*)d_in[0];
    const int* ei = (const int*)d_in[1];  // [2, E]: row = ei[0:E], col = ei[E:2E]
    float* out = (float*)d_out;

    char* ws = (char*)d_ws;
    size_t off = 0;
    auto alloc = [&](size_t bytes) -> void* {
        void* p = ws + off;
        off += (bytes + 511) & ~(size_t)511;
        return p;
    };
    // persistent region
    int4* rec = (int4*)alloc((size_t)N_NODES * 16);
    float* dinv = (float*)alloc((size_t)N_NODES * 4);
    int* gcursor = (int*)alloc(NB * 4);
    int* csrc = (int*)alloc(((size_t)N_EDGES + 64) * 4);  // +64 overread slack
    // transient union: staging (16MB) dead after k_build; zA overlays it.
    // z buffers have N_NODES+1 rows; row N_NODES is the zero row.
    size_t zbytes = (size_t)(N_NODES + 1) * DIM * 2;  // 12.81 MB
    size_t stbytes = (size_t)NB * CAP * 4;            // 16.05 MB
    char* transient = (char*)alloc(stbytes > zbytes ? stbytes : zbytes);
    int* staging = (int*)transient;
    __half* zA = (__half*)transient;
    __half* zB = (__half*)alloc(zbytes);

    hipMemsetAsync(gcursor, 0, NB * 4, stream);

    k_bucket<<<NBLK1, 1024, 0, stream>>>(ei, gcursor, staging);
    k_build<<<NB, 1024, 0, stream>>>(gcursor, staging, rec, dinv, csrc);
    // staging dead from here; zA overlays it. Tail threads zero zero-rows.
    k_z0<<<(N_NODES * DIM / 4) / 256 + 1, 256, 0, stream>>>(emb, dinv, zA, zB);

    int spmvBlocks = (N_NODES + 3) / 4;  // 4 waves/block, 1 wave/node
    // pass1: zA -> zB (z2); pass2: zB -> zA (z3); pass3: gathers zA, reads
    // zB(z2)+zA(z3) own rows, writes out.
    k_spmv<<<spmvBlocks, 256, 0, stream>>>(rec, csrc, zA, zB, nullptr, emb, out, 0);
    k_spmv<<<spmvBlocks, 256, 0, stream>>>(rec, csrc, zB, zA, nullptr, emb, out, 0);
    k_spmv<<<spmvBlocks, 256, 0, stream>>>(rec, csrc, zA, nullptr, zB, emb, out, 2);
}

// Round 15
// 288.963 us; speedup vs baseline: 1.0006x; 1.0006x over previous
//
#include <hip/hip_runtime.h>
#include <hip/hip_bf16.h>
#include <hip/hip_fp16.h>
#include <stdint.h>

// LightGCN on MI355X, round 18 (= exact restore of R16, measured best
// 284.3us).
// R17 post-mortem: direct-placement k_bucket regressed (289.1): halving
// LDS atomics + 32 waves/CU didn't help -> k_bucket is bound by
// same-address LDS-atomic serialization on hot boff counters, which no
// tried restructuring beats. R16's phase-A/B/C/D form is its optimum.
// Probe summary (all from >=2 directions):
// - spmv 58.6x3: TCC/L3 random-gather service floor (FETCH pinned 182MB;
//   write/depth/VALU-insensitive R9/R10/R7).
// - k_bucket: replication null R13, TLP+ R16, direct-placement- R17.
// - k_build: no-redundancy-at-equal-TLP+ R16; fusion- R14; fine-NB- R12.
// - k_z0: standalone beats fused (R14); near launch-overhead floor.

#define N_NODES 100000
#define N_EDGES 3200000
#define DIM 64

#define BSH 9                // 512 nodes per bucket
#define BNODES 512
#define NB 196               // ceil(100000/512)
#define CAP 20480            // staging slots per bucket (mean 16327)

#define CHUNK 8192           // edges per k_bucket block
#define NBLK1 ((N_EDGES + CHUNK - 1) / CHUNK)  // 391

// ---- level 1: bucket edges by dst range (dst>>9); 512 threads ----
__global__ __launch_bounds__(512) void k_bucket(const int* __restrict__ ei,
                                                int* __restrict__ gcursor,
                                                int* __restrict__ staging) {
    __shared__ int stage[CHUNK];            // packed (row<<9)|dstLocal
    __shared__ unsigned char sbkt[CHUNK];   // bucket id per staged entry
    __shared__ int bcnt[NB];
    __shared__ int boff[NB];
    __shared__ int bstart[NB];
    __shared__ int gbase[NB];
    __shared__ int wt[8];

    int t = threadIdx.x;
    int e0 = blockIdx.x * CHUNK;
    int nblk = min(CHUNK, N_EDGES - e0);
    int nvec = nblk >> 2;

    const int4* col4 = (const int4*)(ei + N_EDGES + e0);
    const int4* row4 = (const int4*)(ei + e0);

    for (int i = t; i < NB; i += 512) { bcnt[i] = 0; boff[i] = 0; }
    __syncthreads();

    // phase A: count per bucket
    for (int i = t; i < nvec; i += 512) {
        int4 c = col4[i];
        atomicAdd(&bcnt[c.x >> BSH], 1);
        atomicAdd(&bcnt[c.y >> BSH], 1);
        atomicAdd(&bcnt[c.z >> BSH], 1);
        atomicAdd(&bcnt[c.w >> BSH], 1);
    }
    __syncthreads();

    // phase B: exclusive scan of bcnt -> bstart; reserve global runs
    {
        int v = (t < NB) ? bcnt[t] : 0;
        int lane = t & 63, w = t >> 6;
        int s = v;
#pragma unroll
        for (int off = 1; off < 64; off <<= 1) {
            int u = __shfl_up(s, off);
            if (lane >= off) s += u;
        }
        if (lane == 63) wt[w] = s;
        __syncthreads();
        int wo = 0;
        for (int ww = 0; ww < w; ww++) wo += wt[ww];
        if (t < NB) {
            bstart[t] = s - v + wo;
            gbase[t] = (v > 0) ? atomicAdd(&gcursor[t], v) : 0;
        }
    }
    __syncthreads();

    // phase C: place edges into LDS, bucket-sorted; remember bucket id
    for (int i = t; i < nvec; i += 512) {
        int4 c = col4[i];
        int4 r = row4[i];
        int b0 = c.x >> BSH, b1 = c.y >> BSH, b2 = c.z >> BSH, b3 = c.w >> BSH;
        int p0 = bstart[b0] + atomicAdd(&boff[b0], 1);
        int p1 = bstart[b1] + atomicAdd(&boff[b1], 1);
        int p2 = bstart[b2] + atomicAdd(&boff[b2], 1);
        int p3 = bstart[b3] + atomicAdd(&boff[b3], 1);
        stage[p0] = (r.x << BSH) | (c.x & (BNODES - 1)); sbkt[p0] = (unsigned char)b0;
        stage[p1] = (r.y << BSH) | (c.y & (BNODES - 1)); sbkt[p1] = (unsigned char)b1;
        stage[p2] = (r.z << BSH) | (c.z & (BNODES - 1)); sbkt[p2] = (unsigned char)b2;
        stage[p3] = (r.w << BSH) | (c.w & (BNODES - 1)); sbkt[p3] = (unsigned char)b3;
    }
    __syncthreads();

    // phase D: flush runs contiguously (coalesced across the wave)
    for (int i = t; i < nblk; i += 512) {
        int e = stage[i];
        int b = sbkt[i];
        staging[(size_t)b * CAP + gbase[b] + (i - bstart[b])] = e;
    }
}

// ---- level 2: CSR build; ONE block of 1024 threads per bucket ----
// Reads the bucket segment once; counts 512 nodes (3.2M total atomics);
// scans; scatters into the bucket's contiguous csrc range (single owner).
__global__ __launch_bounds__(1024) void k_build(const int* __restrict__ gcursor,
                                                const int* __restrict__ staging,
                                                int4* __restrict__ rec,
                                                float* __restrict__ dinv,
                                                int* __restrict__ csrc) {
    __shared__ int ldeg[BNODES];
    __shared__ int lcur[BNODES];
    __shared__ int gsc[NB];
    __shared__ int wtt[16];

    int b = blockIdx.x;
    int t = threadIdx.x;
    int lane = t & 63, w = t >> 6;
    int n0 = b << BSH;
    int nloc = min(BNODES, N_NODES - n0);
    int cnt = gcursor[b];
    const int* st = staging + (size_t)b * CAP;

    if (t < BNODES) ldeg[t] = 0;

    // bucketStart[b] via in-block exclusive scan of gcursor[0..NB)
    {
        int v = (t < NB) ? gcursor[t] : 0;
        int ss = v;
#pragma unroll
        for (int off = 1; off < 64; off <<= 1) {
            int u = __shfl_up(ss, off);
            if (lane >= off) ss += u;
        }
        if (lane == 63) wtt[w] = ss;
        __syncthreads();
        int wo = 0;
        for (int ww = 0; ww < w; ww++) wo += wtt[ww];
        if (t < NB) gsc[t] = ss - v + wo;
    }
    __syncthreads();
    int bstartB = gsc[b];

    // count the bucket's 512 nodes (single pass, no redundancy)
    for (int i = t; i < cnt; i += 1024) {
        atomicAdd(&ldeg[st[i] & (BNODES - 1)], 1);
    }
    __syncthreads();

    // scan over 512 counters (1 per thread, threads 0..511 over 8 waves)
    int a = (t < BNODES) ? ldeg[t] : 0;
    int ss = a;
#pragma unroll
    for (int off = 1; off < 64; off <<= 1) {
        int u = __shfl_up(ss, off);
        if (lane >= off) ss += u;
    }
    if (lane == 63) wtt[w] = ss;
    __syncthreads();
    int wo = 0;
    for (int ww = 0; ww < w; ww++) wo += wtt[ww];
    int excl = ss - a + wo;

    if (t < BNODES) {
        int gb = bstartB + excl;
        lcur[t] = gb;
        if (t < nloc) {
            int n = n0 + t;
            float di = (a > 0) ? rsqrtf((float)a) : 0.0f;
            rec[n] = make_int4(gb, a, __float_as_int(di), 0);
            dinv[n] = di;
        }
    }
    __syncthreads();

    // scatter into this bucket's csrc range (single owner -> L2 combining)
    for (int i = t; i < cnt; i += 1024) {
        int e = st[i];
        int p = atomicAdd(&lcur[e & (BNODES - 1)], 1);
        csrc[p] = e >> BSH;
    }
}

// z0 = fp16(emb * dinv[node]); tail threads zero the zero rows of zA/zB
__global__ void k_z0(const float* __restrict__ emb, const float* __restrict__ dinv,
                     __half* __restrict__ zA, __half* __restrict__ zB) {
    const int total = (N_NODES * DIM) / 4;  // 1.6M groups of 4
    int i = blockIdx.x * blockDim.x + threadIdx.x;
    if (i >= total) {
        int r = i - total;
        if (r < 16) ((uint2*)(zA + (size_t)N_NODES * DIM))[r] = make_uint2(0, 0);
        else if (r < 32) ((uint2*)(zB + (size_t)N_NODES * DIM))[r - 16] = make_uint2(0, 0);
        return;
    }
    float di = dinv[(i * 4) >> 6];
    const float4 v = ((const float4*)emb)[i];
    union { ushort h[4]; uint2 u; } pk;
    __half h0 = __float2half(v.x * di);
    __half h1 = __float2half(v.y * di);
    __half h2 = __float2half(v.z * di);
    __half h3 = __float2half(v.w * di);
    pk.h[0] = *(ushort*)&h0; pk.h[1] = *(ushort*)&h1;
    pk.h[2] = *(ushort*)&h2; pk.h[3] = *(ushort*)&h3;
    ((uint2*)zA)[i] = pk.u;
}

// ---- SpMV: one wave per dst node; exact ceil(deg/8) gather groups of 8;
// fp16 rows, packed half2 accumulate; invalid slots -> zero row.
// mode 0: write z_out = x*dinv (fp16) only.
// mode 2: final: out = 0.25*(emb + sqrt(deg)*(z2+z3) + x3); no z write.
__global__ __launch_bounds__(256) void k_spmv(
    const int4* __restrict__ rec, const int* __restrict__ csrc,
    const __half* __restrict__ z, __half* __restrict__ znext,
    const __half* __restrict__ zprev, const float* __restrict__ emb,
    float* __restrict__ out, int mode) {
    int wave = (blockIdx.x * blockDim.x + threadIdx.x) >> 6;
    int lane = threadIdx.x & 63;
    if (wave >= N_NODES) return;
    int g = lane >> 3;   // edge slot within group 0..7
    int l = lane & 7;    // feature chunk: features [l*8, l*8+8)

    int4 nr = rec[wave];          // broadcast load
    int start = nr.x;
    int cnt = nr.y;
    float di = __int_as_float(nr.z);
    int ng = (cnt + 7) >> 3;      // gather groups (wave-uniform)

    __half2 hz = __float2half2_rn(0.0f);
    __half2 hacc0 = hz, hacc1 = hz, hacc2 = hz, hacc3 = hz;

#define GIDX(KK, SV)                                 \
    int e_##SV = (KK) * 8 + g;                       \
    int SV = csrc[start + e_##SV];                   \
    SV = (e_##SV < cnt) ? SV : N_NODES;

#define GFETCH(SV, VV)                               \
    uint4 VV = *((const uint4*)(z + ((size_t)SV << 6)) + l);

#define GADD(VV)                                                          \
    do {                                                                  \
        const __half2* hv = (const __half2*)&VV;                          \
        hacc0 = __hadd2(hacc0, hv[0]);                                    \
        hacc1 = __hadd2(hacc1, hv[1]);                                    \
        hacc2 = __hadd2(hacc2, hv[2]);                                    \
        hacc3 = __hadd2(hacc3, hv[3]);                                    \
    } while (0)

    int k = 0;
    for (; k + 4 <= ng; k += 4) {
        GIDX(k + 0, s0) GIDX(k + 1, s1) GIDX(k + 2, s2) GIDX(k + 3, s3)
        GFETCH(s0, v0) GFETCH(s1, v1) GFETCH(s2, v2) GFETCH(s3, v3)
        GADD(v0); GADD(v1); GADD(v2); GADD(v3);
    }
    int rem = ng - k;           // wave-uniform 0..3
    if (rem > 0) {
        GIDX(k + 0, t0)
        if (rem > 1) {
            GIDX(k + 1, t1)
            if (rem > 2) {
                GIDX(k + 2, t2)
                GFETCH(t0, w0) GFETCH(t1, w1) GFETCH(t2, w2)
                GADD(w0); GADD(w1); GADD(w2);
            } else {
                GFETCH(t0, w0) GFETCH(t1, w1)
                GADD(w0); GADD(w1);
            }
        } else {
            GFETCH(t0, w0)
            GADD(w0);
        }
    }
#undef GIDX
#undef GFETCH
#undef GADD

    // packed reduce across the 8 edge-slot groups (lane bits 3,4,5)
#pragma unroll
    for (int off = 8; off <= 32; off <<= 1) {
        int b0 = __shfl_xor(*(int*)&hacc0, off);
        int b1 = __shfl_xor(*(int*)&hacc1, off);
        int b2 = __shfl_xor(*(int*)&hacc2, off);
        int b3 = __shfl_xor(*(int*)&hacc3, off);
        hacc0 = __hadd2(hacc0, *(__half2*)&b0);
        hacc1 = __hadd2(hacc1, *(__half2*)&b1);
        hacc2 = __hadd2(hacc2, *(__half2*)&b2);
        hacc3 = __hadd2(hacc3, *(__half2*)&b3);
    }

    if (lane < 8) {  // lane == l, holds features [l*8, l*8+8)
        size_t o = (size_t)wave * DIM + lane * 8;
        float x[8];   // x_{k+1} for this node = di * sum
        x[0] = __low2float(hacc0) * di; x[1] = __high2float(hacc0) * di;
        x[2] = __low2float(hacc1) * di; x[3] = __high2float(hacc1) * di;
        x[4] = __low2float(hacc2) * di; x[5] = __high2float(hacc2) * di;
        x[6] = __low2float(hacc3) * di; x[7] = __high2float(hacc3) * di;

        if (mode == 0) {
            union { ushort h[8]; uint4 u; } pk;
#pragma unroll
            for (int j = 0; j < 8; j++) {
                __half hh = __float2half(x[j] * di);
                pk.h[j] = *(ushort*)&hh;
            }
            *((uint4*)(znext + o)) = pk.u;
        } else {
            float sdeg = (cnt > 0) ? sqrtf((float)cnt) : 0.0f;
            uint4 v2 = *((const uint4*)(zprev + o));  // z2 (own row)
            uint4 v3 = *((const uint4*)(z + o));      // z3 (own row)
            const __half2* h2 = (const __half2*)&v2;
            const __half2* h3 = (const __half2*)&v3;
            float4 e0 = ((const float4*)(emb + o))[0];
            float4 e1 = ((const float4*)(emb + o))[1];
            float zs[8];
#pragma unroll
            for (int j = 0; j < 4; j++) {
                float2 a2 = __half22float2(h2[j]);
                float2 a3 = __half22float2(h3[j]);
                zs[2 * j] = a2.x + a3.x;
                zs[2 * j + 1] = a2.y + a3.y;
            }
            float4 o0 = make_float4(
                (e0.x + sdeg * zs[0] + x[0]) * 0.25f,
                (e0.y + sdeg * zs[1] + x[1]) * 0.25f,
                (e0.z + sdeg * zs[2] + x[2]) * 0.25f,
                (e0.w + sdeg * zs[3] + x[3]) * 0.25f);
            float4 o1 = make_float4(
                (e1.x + sdeg * zs[4] + x[4]) * 0.25f,
                (e1.y + sdeg * zs[5] + x[5]) * 0.25f,
                (e1.z + sdeg * zs[6] + x[6]) * 0.25f,
                (e1.w + sdeg * zs[7] + x[7]) * 0.25f);
            ((float4*)(out + o))[0] = o0;
            ((float4*)(out + o))[1] = o1;
        }
    }
}

extern "C" void kernel_launch(void* const* d_in, const int* in_sizes, int n_in,
                              void* d_out, int out_size, void* d_ws, size_t ws_size,
                              hipStream_t stream) {
    const float* emb = (const float*)d_in[0];
    const int* ei = (const int*)d_in[1];  // [2, E]: row = ei[0:E], col = ei[E:2E]
    float* out = (float*)d_out;

    char* ws = (char*)d_ws;
    size_t off = 0;
    auto alloc = [&](size_t bytes) -> void* {
        void* p = ws + off;
        off += (bytes + 511) & ~(size_t)511;
        return p;
    };
    // persistent region
    int4* rec = (int4*)alloc((size_t)N_NODES * 16);
    float* dinv = (float*)alloc((size_t)N_NODES * 4);
    int* gcursor = (int*)alloc(NB * 4);
    int* csrc = (int*)alloc(((size_t)N_EDGES + 64) * 4);  // +64 overread slack
    // transient union: staging (16MB) dead after k_build; zA overlays it.
    // z buffers have N_NODES+1 rows; row N_NODES is the zero row.
    size_t zbytes = (size_t)(N_NODES + 1) * DIM * 2;  // 12.81 MB
    size_t stbytes = (size_t)NB * CAP * 4;            // 16.05 MB
    char* transient = (char*)alloc(stbytes > zbytes ? stbytes : zbytes);
    int* staging = (int*)transient;
    __half* zA = (__half*)transient;
    __half* zB = (__half*)alloc(zbytes);

    hipMemsetAsync(gcursor, 0, NB * 4, stream);

    k_bucket<<<NBLK1, 512, 0, stream>>>(ei, gcursor, staging);
    k_build<<<NB, 1024, 0, stream>>>(gcursor, staging, rec, dinv, csrc);
    // staging dead from here; zA overlays it. Tail threads zero zero-rows.
    k_z0<<<(N_NODES * DIM / 4) / 256 + 1, 256, 0, stream>>>(emb, dinv, zA, zB);

    int spmvBlocks = (N_NODES + 3) / 4;  // 4 waves/block, 1 wave/node
    // pass1: zA -> zB (z2); pass2: zB -> zA (z3); pass3: gathers zA, reads
    // zB(z2)+zA(z3) own rows, writes out.
    k_spmv<<<spmvBlocks, 256, 0, stream>>>(rec, csrc, zA, zB, nullptr, emb, out, 0);
    k_spmv<<<spmvBlocks, 256, 0, stream>>>(rec, csrc, zB, zA, nullptr, emb, out, 0);
    k_spmv<<<spmvBlocks, 256, 0, stream>>>(rec, csrc, zA, nullptr, zB, emb, out, 2);
}

// Round 17
// 277.113 us; speedup vs baseline: 1.0434x; 1.0428x over previous
//
#include <hip/hip_runtime.h>
#include <hip/hip_bf16.h>
#include <hip/hip_fp16.h>
#include <stdint.h>

// LightGCN on MI355X, round 20.
// R19 post-mortem: fp8 failed absmax by 8.7% (6.1e-5 vs 5.6e-5), and the
// error model NAILS it: the epilogue recovery x_k = sdeg*z_k amplifies
// fp8 quant error by sdeg~5.66 -> 0.25*5.66*2*2e-5 ~ 5.7e-5 of the 6.1e-5.
// The fp8 GATHER path contributes only ~1e-5.
// R20: keep fp8 gathers (64B = ONE line/row; footprint 6.4MB), restore
// the f32 out-accumulator RMW (mode0 out=emb+x1; mode1 out+=x2; mode2
// out=(out+x3)*0.25) — x_k enters out in f32, no recovery term. R9 proved
// this streaming RMW is free (spmv service-bound on random gathers).
// Predicted absmax ~2e-5 (passes, ~2x margin).
// FINAL pre-commit: spmv >=55us or absmax fail -> revert R16, ROOFLINE.
// k_bucket(512t)/k_build(196x1024)/k_z0(fp8) = R19 verbatim.

#define N_NODES 100000
#define N_EDGES 3200000
#define DIM 64
#define ZSCALE 4096.0f
#define ZSCALE_INV (1.0f / 4096.0f)

#define BSH 9                // 512 nodes per bucket
#define BNODES 512
#define NB 196               // ceil(100000/512)
#define CAP 20480            // staging slots per bucket (mean 16327)

#define CHUNK 8192           // edges per k_bucket block
#define NBLK1 ((N_EDGES + CHUNK - 1) / CHUNK)  // 391

typedef __attribute__((ext_vector_type(2))) float f32x2;

__device__ __forceinline__ uint2 enc8(const float* x) {
    int a = 0, b = 0;
    a = __builtin_amdgcn_cvt_pk_fp8_f32(x[0], x[1], a, false);
    a = __builtin_amdgcn_cvt_pk_fp8_f32(x[2], x[3], a, true);
    b = __builtin_amdgcn_cvt_pk_fp8_f32(x[4], x[5], b, false);
    b = __builtin_amdgcn_cvt_pk_fp8_f32(x[6], x[7], b, true);
    return make_uint2((unsigned)a, (unsigned)b);
}

// ---- level 1: bucket edges by dst range (dst>>9); 512 threads ----
__global__ __launch_bounds__(512) void k_bucket(const int* __restrict__ ei,
                                                int* __restrict__ gcursor,
                                                int* __restrict__ staging) {
    __shared__ int stage[CHUNK];            // packed (row<<9)|dstLocal
    __shared__ unsigned char sbkt[CHUNK];   // bucket id per staged entry
    __shared__ int bcnt[NB];
    __shared__ int boff[NB];
    __shared__ int bstart[NB];
    __shared__ int gbase[NB];
    __shared__ int wt[8];

    int t = threadIdx.x;
    int e0 = blockIdx.x * CHUNK;
    int nblk = min(CHUNK, N_EDGES - e0);
    int nvec = nblk >> 2;

    const int4* col4 = (const int4*)(ei + N_EDGES + e0);
    const int4* row4 = (const int4*)(ei + e0);

    for (int i = t; i < NB; i += 512) { bcnt[i] = 0; boff[i] = 0; }
    __syncthreads();

    // phase A: count per bucket
    for (int i = t; i < nvec; i += 512) {
        int4 c = col4[i];
        atomicAdd(&bcnt[c.x >> BSH], 1);
        atomicAdd(&bcnt[c.y >> BSH], 1);
        atomicAdd(&bcnt[c.z >> BSH], 1);
        atomicAdd(&bcnt[c.w >> BSH], 1);
    }
    __syncthreads();

    // phase B: exclusive scan of bcnt -> bstart; reserve global runs
    {
        int v = (t < NB) ? bcnt[t] : 0;
        int lane = t & 63, w = t >> 6;
        int s = v;
#pragma unroll
        for (int off = 1; off < 64; off <<= 1) {
            int u = __shfl_up(s, off);
            if (lane >= off) s += u;
        }
        if (lane == 63) wt[w] = s;
        __syncthreads();
        int wo = 0;
        for (int ww = 0; ww < w; ww++) wo += wt[ww];
        if (t < NB) {
            bstart[t] = s - v + wo;
            gbase[t] = (v > 0) ? atomicAdd(&gcursor[t], v) : 0;
        }
    }
    __syncthreads();

    // phase C: place edges into LDS, bucket-sorted; remember bucket id
    for (int i = t; i < nvec; i += 512) {
        int4 c = col4[i];
        int4 r = row4[i];
        int b0 = c.x >> BSH, b1 = c.y >> BSH, b2 = c.z >> BSH, b3 = c.w >> BSH;
        int p0 = bstart[b0] + atomicAdd(&boff[b0], 1);
        int p1 = bstart[b1] + atomicAdd(&boff[b1], 1);
        int p2 = bstart[b2] + atomicAdd(&boff[b2], 1);
        int p3 = bstart[b3] + atomicAdd(&boff[b3], 1);
        stage[p0] = (r.x << BSH) | (c.x & (BNODES - 1)); sbkt[p0] = (unsigned char)b0;
        stage[p1] = (r.y << BSH) | (c.y & (BNODES - 1)); sbkt[p1] = (unsigned char)b1;
        stage[p2] = (r.z << BSH) | (c.z & (BNODES - 1)); sbkt[p2] = (unsigned char)b2;
        stage[p3] = (r.w << BSH) | (c.w & (BNODES - 1)); sbkt[p3] = (unsigned char)b3;
    }
    __syncthreads();

    // phase D: flush runs contiguously (coalesced across the wave)
    for (int i = t; i < nblk; i += 512) {
        int e = stage[i];
        int b = sbkt[i];
        staging[(size_t)b * CAP + gbase[b] + (i - bstart[b])] = e;
    }
}

// ---- level 2: CSR build; ONE block of 1024 threads per bucket ----
__global__ __launch_bounds__(1024) void k_build(const int* __restrict__ gcursor,
                                                const int* __restrict__ staging,
                                                int4* __restrict__ rec,
                                                float* __restrict__ dinv,
                                                int* __restrict__ csrc) {
    __shared__ int ldeg[BNODES];
    __shared__ int lcur[BNODES];
    __shared__ int gsc[NB];
    __shared__ int wtt[16];

    int b = blockIdx.x;
    int t = threadIdx.x;
    int lane = t & 63, w = t >> 6;
    int n0 = b << BSH;
    int nloc = min(BNODES, N_NODES - n0);
    int cnt = gcursor[b];
    const int* st = staging + (size_t)b * CAP;

    if (t < BNODES) ldeg[t] = 0;

    // bucketStart[b] via in-block exclusive scan of gcursor[0..NB)
    {
        int v = (t < NB) ? gcursor[t] : 0;
        int ss = v;
#pragma unroll
        for (int off = 1; off < 64; off <<= 1) {
            int u = __shfl_up(ss, off);
            if (lane >= off) ss += u;
        }
        if (lane == 63) wtt[w] = ss;
        __syncthreads();
        int wo = 0;
        for (int ww = 0; ww < w; ww++) wo += wtt[ww];
        if (t < NB) gsc[t] = ss - v + wo;
    }
    __syncthreads();
    int bstartB = gsc[b];

    // count the bucket's 512 nodes (single pass, no redundancy)
    for (int i = t; i < cnt; i += 1024) {
        atomicAdd(&ldeg[st[i] & (BNODES - 1)], 1);
    }
    __syncthreads();

    // scan over 512 counters (1 per thread, threads 0..511 over 8 waves)
    int a = (t < BNODES) ? ldeg[t] : 0;
    int ss = a;
#pragma unroll
    for (int off = 1; off < 64; off <<= 1) {
        int u = __shfl_up(ss, off);
        if (lane >= off) ss += u;
    }
    if (lane == 63) wtt[w] = ss;
    __syncthreads();
    int wo = 0;
    for (int ww = 0; ww < w; ww++) wo += wtt[ww];
    int excl = ss - a + wo;

    if (t < BNODES) {
        int gb = bstartB + excl;
        lcur[t] = gb;
        if (t < nloc) {
            int n = n0 + t;
            float di = (a > 0) ? rsqrtf((float)a) : 0.0f;
            rec[n] = make_int4(gb, a, __float_as_int(di), 0);
            dinv[n] = di;
        }
    }
    __syncthreads();

    // scatter into this bucket's csrc range (single owner -> L2 combining)
    for (int i = t; i < cnt; i += 1024) {
        int e = st[i];
        int p = atomicAdd(&lcur[e & (BNODES - 1)], 1);
        csrc[p] = e >> BSH;
    }
}

// z0 = fp8(emb * dinv * S); 8 features (8 B) per thread.
// Tail threads zero the 64B zero rows of zA/zB.
__global__ void k_z0(const float* __restrict__ emb, const float* __restrict__ dinv,
                     unsigned char* __restrict__ zA, unsigned char* __restrict__ zB) {
    const int total = N_NODES * 8;  // groups of 8 features
    int i = blockIdx.x * blockDim.x + threadIdx.x;
    if (i >= total) {
        int r = i - total;
        if (r < 8) ((uint2*)(zA + (size_t)N_NODES * DIM))[r] = make_uint2(0, 0);
        else if (r < 16) ((uint2*)(zB + (size_t)N_NODES * DIM))[r - 8] = make_uint2(0, 0);
        return;
    }
    int node = i >> 3;
    int eo = (i << 3);             // element offset = node*64 + (i&7)*8
    float diS = dinv[node] * ZSCALE;
    float4 v0 = ((const float4*)(emb + eo))[0];
    float4 v1 = ((const float4*)(emb + eo))[1];
    float x[8] = {v0.x * diS, v0.y * diS, v0.z * diS, v0.w * diS,
                  v1.x * diS, v1.y * diS, v1.z * diS, v1.w * diS};
    ((uint2*)zA)[i] = enc8(x);
}

// ---- SpMV: one wave per dst node; exact ceil(deg/8) gather groups of 8;
// fp8 rows (64B = ONE line), HW cvt + v_pk_add_f32 accumulate; invalid
// slots -> zero row. x enters out in f32 (no sdeg recovery).
// mode 0: out = emb + x;          znext = fp8(di^2 * sum)  [S cancels]
// mode 1: out += x;               znext = fp8(di^2 * sum)
// mode 2: out = (out + x) * 0.25; no z write
__global__ __launch_bounds__(256) void k_spmv(
    const int4* __restrict__ rec, const int* __restrict__ csrc,
    const unsigned char* __restrict__ z, unsigned char* __restrict__ znext,
    const float* __restrict__ emb, float* __restrict__ out, int mode) {
    int wave = (blockIdx.x * blockDim.x + threadIdx.x) >> 6;
    int lane = threadIdx.x & 63;
    if (wave >= N_NODES) return;
    int g = lane >> 3;   // edge slot within group 0..7
    int l = lane & 7;    // feature chunk: features [l*8, l*8+8)

    int4 nr = rec[wave];          // broadcast load
    int start = nr.x;
    int cnt = nr.y;
    float di = __int_as_float(nr.z);
    int ng = (cnt + 7) >> 3;      // gather groups (wave-uniform)

    f32x2 acc0 = {0.0f, 0.0f}, acc1 = {0.0f, 0.0f};
    f32x2 acc2 = {0.0f, 0.0f}, acc3 = {0.0f, 0.0f};

#define GIDX(KK, SV)                                 \
    int e_##SV = (KK) * 8 + g;                       \
    int SV = csrc[start + e_##SV];                   \
    SV = (e_##SV < cnt) ? SV : N_NODES;

#define GFETCH(SV, VV)                               \
    uint2 VV = *((const uint2*)(z + ((size_t)SV << 6)) + l);

#define GADD(VV)                                                            \
    do {                                                                    \
        acc0 += __builtin_amdgcn_cvt_pk_f32_fp8((int)(VV).x, false);        \
        acc1 += __builtin_amdgcn_cvt_pk_f32_fp8((int)(VV).x, true);         \
        acc2 += __builtin_amdgcn_cvt_pk_f32_fp8((int)(VV).y, false);        \
        acc3 += __builtin_amdgcn_cvt_pk_f32_fp8((int)(VV).y, true);         \
    } while (0)

    int k = 0;
    for (; k + 4 <= ng; k += 4) {
        GIDX(k + 0, s0) GIDX(k + 1, s1) GIDX(k + 2, s2) GIDX(k + 3, s3)
        GFETCH(s0, v0) GFETCH(s1, v1) GFETCH(s2, v2) GFETCH(s3, v3)
        GADD(v0); GADD(v1); GADD(v2); GADD(v3);
    }
    int rem = ng - k;           // wave-uniform 0..3
    if (rem > 0) {
        GIDX(k + 0, t0)
        if (rem > 1) {
            GIDX(k + 1, t1)
            if (rem > 2) {
                GIDX(k + 2, t2)
                GFETCH(t0, w0) GFETCH(t1, w1) GFETCH(t2, w2)
                GADD(w0); GADD(w1); GADD(w2);
            } else {
                GFETCH(t0, w0) GFETCH(t1, w1)
                GADD(w0); GADD(w1);
            }
        } else {
            GFETCH(t0, w0)
            GADD(w0);
        }
    }
#undef GIDX
#undef GFETCH
#undef GADD

    // reduce across the 8 edge-slot groups (lane bits 3,4,5)
#pragma unroll
    for (int off = 8; off <= 32; off <<= 1) {
        f32x2 t0, t1, t2, t3;
        t0[0] = __shfl_xor(acc0[0], off); t0[1] = __shfl_xor(acc0[1], off);
        t1[0] = __shfl_xor(acc1[0], off); t1[1] = __shfl_xor(acc1[1], off);
        t2[0] = __shfl_xor(acc2[0], off); t2[1] = __shfl_xor(acc2[1], off);
        t3[0] = __shfl_xor(acc3[0], off); t3[1] = __shfl_xor(acc3[1], off);
        acc0 += t0; acc1 += t1; acc2 += t2; acc3 += t3;
    }

    if (lane < 8) {  // lane == l, holds features [l*8, l*8+8)
        size_t o = (size_t)wave * DIM + lane * 8;  // elem offset == byte offset in z
        float diS = di * ZSCALE_INV;  // x = di * sum_scaled / S
        float x[8] = {acc0[0] * diS, acc0[1] * diS, acc1[0] * diS, acc1[1] * diS,
                      acc2[0] * diS, acc2[1] * diS, acc3[0] * diS, acc3[1] * diS};

        float4 o0, o1;
        if (mode == 0) {
            float4 e0 = ((const float4*)(emb + o))[0];
            float4 e1 = ((const float4*)(emb + o))[1];
            o0 = make_float4(e0.x + x[0], e0.y + x[1], e0.z + x[2], e0.w + x[3]);
            o1 = make_float4(e1.x + x[4], e1.y + x[5], e1.z + x[6], e1.w + x[7]);
        } else if (mode == 1) {
            float4 a0 = ((const float4*)(out + o))[0];
            float4 a1 = ((const float4*)(out + o))[1];
            o0 = make_float4(a0.x + x[0], a0.y + x[1], a0.z + x[2], a0.w + x[3]);
            o1 = make_float4(a1.x + x[4], a1.y + x[5], a1.z + x[6], a1.w + x[7]);
        } else {
            float4 a0 = ((const float4*)(out + o))[0];
            float4 a1 = ((const float4*)(out + o))[1];
            o0 = make_float4((a0.x + x[0]) * 0.25f, (a0.y + x[1]) * 0.25f,
                             (a0.z + x[2]) * 0.25f, (a0.w + x[3]) * 0.25f);
            o1 = make_float4((a1.x + x[4]) * 0.25f, (a1.y + x[5]) * 0.25f,
                             (a1.z + x[6]) * 0.25f, (a1.w + x[7]) * 0.25f);
        }
        ((float4*)(out + o))[0] = o0;
        ((float4*)(out + o))[1] = o1;

        if (mode != 2) {
            float d2 = di * di;   // znext_scaled = di^2 * sum_scaled (S cancels)
            float zx[8] = {acc0[0] * d2, acc0[1] * d2, acc1[0] * d2, acc1[1] * d2,
                           acc2[0] * d2, acc2[1] * d2, acc3[0] * d2, acc3[1] * d2};
            *((uint2*)(znext + o)) = enc8(zx);
        }
    }
}

extern "C" void kernel_launch(void* const* d_in, const int* in_sizes, int n_in,
                              void* d_out, int out_size, void* d_ws, size_t ws_size,
                              hipStream_t stream) {
    const float* emb = (const float*)d_in[0];
    const int* ei = (const int*)d_in[1];  // [2, E]: row = ei[0:E], col = ei[E:2E]
    float* out = (float*)d_out;

    char* ws = (char*)d_ws;
    size_t off = 0;
    auto alloc = [&](size_t bytes) -> void* {
        void* p = ws + off;
        off += (bytes + 511) & ~(size_t)511;
        return p;
    };
    // persistent region
    int4* rec = (int4*)alloc((size_t)N_NODES * 16);
    float* dinv = (float*)alloc((size_t)N_NODES * 4);
    int* gcursor = (int*)alloc(NB * 4);
    int* csrc = (int*)alloc(((size_t)N_EDGES + 64) * 4);  // +64 overread slack
    // transient union: staging (16MB) dead after k_build; zA overlays it.
    // z buffers: (N_NODES+1) rows x 64 B fp8; row N_NODES is the zero row.
    size_t zbytes = (size_t)(N_NODES + 1) * DIM;       // 6.4 MB
    size_t stbytes = (size_t)NB * CAP * 4;             // 16.05 MB
    char* transient = (char*)alloc(stbytes > zbytes ? stbytes : zbytes);
    int* staging = (int*)transient;
    unsigned char* zA = (unsigned char*)transient;
    unsigned char* zB = (unsigned char*)alloc(zbytes);

    hipMemsetAsync(gcursor, 0, NB * 4, stream);

    k_bucket<<<NBLK1, 512, 0, stream>>>(ei, gcursor, staging);
    k_build<<<NB, 1024, 0, stream>>>(gcursor, staging, rec, dinv, csrc);
    // staging dead from here; zA overlays it. Tail threads zero zero-rows.
    k_z0<<<(N_NODES * 8) / 256 + 1, 256, 0, stream>>>(emb, dinv, zA, zB);

    int spmvBlocks = (N_NODES + 3) / 4;  // 4 waves/block, 1 wave/node
    // pass1: gather zA -> out=emb+x1, write zB; pass2: gather zB -> out+=x2,
    // write zA; pass3: gather zA -> out=(out+x3)*0.25.
    k_spmv<<<spmvBlocks, 256, 0, stream>>>(rec, csrc, zA, zB, emb, out, 0);
    k_spmv<<<spmvBlocks, 256, 0, stream>>>(rec, csrc, zB, zA, emb, out, 1);
    k_spmv<<<spmvBlocks, 256, 0, stream>>>(rec, csrc, zA, nullptr, emb, out, 2);
}